// Round 2
// baseline (1531.579 us; speedup 1.0000x reference)
//
#include <hip/hip_runtime.h>

typedef unsigned int uint;
typedef short bf16x8 __attribute__((ext_vector_type(8)));
typedef float f32x4 __attribute__((ext_vector_type(4)));

// ---------- bf16 helpers (bit-level, RNE) ----------
__device__ __forceinline__ unsigned short f2b(float f) {
    uint u = __builtin_bit_cast(uint, f);
    u += 0x7fffu + ((u >> 16) & 1u);
    return (unsigned short)(u >> 16);
}
__device__ __forceinline__ float b2f(unsigned short h) {
    uint u = ((uint)h) << 16;
    return __builtin_bit_cast(float, u);
}

// ---------- weight prep ----------
__global__ __launch_bounds__(256) void convert_bf16_kernel(const float* __restrict__ src,
                                                           unsigned short* __restrict__ dst, int n) {
    int idx = blockIdx.x * 256 + threadIdx.x;
    if (idx < n) dst[idx] = f2b(src[idx]);
}

// src is (K, N) row-major; dst is (N, K) row-major (i.e. B^T), bf16.
__global__ __launch_bounds__(256) void transpose_to_bf16_kernel(const float* __restrict__ src,
                                                                unsigned short* __restrict__ dst,
                                                                int K, int N) {
    long long idx = (long long)blockIdx.x * 256 + threadIdx.x;
    if (idx >= (long long)K * N) return;
    int k = (int)(idx / N);
    int n = (int)(idx % N);
    dst[(long long)n * K + k] = f2b(src[idx]);
}

// ---------- im2col: input (B,C,H,W) -> A (16384, 768) bf16, k = c*256+p*16+q ----------
__global__ __launch_bounds__(256) void im2col_kernel(const float* __restrict__ in,
                                                     unsigned short* __restrict__ out) {
    long long idx = (long long)blockIdx.x * 256 + threadIdx.x; // < 16384*768
    int k = (int)(idx % 768);
    int n = (int)(idx / 768);
    int b = n >> 10, t = n & 1023;
    int hp = t >> 5, wp = t & 31;
    int c = k >> 8, rm = k & 255;
    int p = rm >> 4, q = rm & 15;
    long long src = (((long long)(b * 3 + c) * 512) + hp * 16 + p) * 512 + wp * 16 + q;
    out[idx] = f2b(in[src]);
}

// ---------- LayerNorm + sinusoidal PE -> bf16 ----------
__global__ __launch_bounds__(256) void ln_pe_kernel(const float* __restrict__ xe,
                                                    const float* __restrict__ g,
                                                    const float* __restrict__ bb,
                                                    unsigned short* __restrict__ xb) {
    int row = blockIdx.x;            // 0..16383
    int pos = row & 1023;
    const float* xr = xe + (long long)row * 768;
    float v0 = xr[threadIdx.x];
    float v1 = xr[threadIdx.x + 256];
    float v2 = xr[threadIdx.x + 512];
    float s = v0 + v1 + v2;
    float sq = v0 * v0 + v1 * v1 + v2 * v2;
    for (int o = 32; o > 0; o >>= 1) {
        s  += __shfl_down(s, o, 64);
        sq += __shfl_down(sq, o, 64);
    }
    __shared__ float ps[4], pq[4];
    int w = threadIdx.x >> 6, lane = threadIdx.x & 63;
    if (lane == 0) { ps[w] = s; pq[w] = sq; }
    __syncthreads();
    float ts = ps[0] + ps[1] + ps[2] + ps[3];
    float tq = pq[0] + pq[1] + pq[2] + pq[3];
    float mean = ts * (1.0f / 768.0f);
    float var  = tq * (1.0f / 768.0f) - mean * mean;
    float inv  = rsqrtf(var + 1e-5f);
    #pragma unroll
    for (int dd = 0; dd < 3; dd++) {
        int d = threadIdx.x + dd * 256;
        float val = (dd == 0) ? v0 : (dd == 1) ? v1 : v2;
        float y = (val - mean) * inv * g[d] + bb[d];
        float freq = __expf(-(float)(d & ~1) * (9.210340371976184f / 768.0f));
        float ang = (float)pos * freq;
        y += (d & 1) ? cosf(ang) : sinf(ang);
        xb[(long long)row * 768 + d] = f2b(y);
    }
}

// ---------- generic bf16 MFMA GEMM: C = A(MxK) * BT(N rows, ldb stride)^T ----------
// v = acc (+ bias[gn]); if epi==1 gelu(v); if accumF v += outF[off];
// if residB v += b2f(residB[off]); write outF/outB if non-null.
__global__ __launch_bounds__(256) void gemm_bt_kernel(const unsigned short* __restrict__ A,
                                                      const unsigned short* __restrict__ BT,
                                                      const float* __restrict__ bias,
                                                      const unsigned short* __restrict__ residB,
                                                      float* __restrict__ outF,
                                                      unsigned short* __restrict__ outB,
                                                      int M, int N, int K, int ldb,
                                                      int epi, int accumF) {
    __shared__ unsigned short As[64 * 32];
    __shared__ unsigned short Bs[64 * 32];
    const int tid = threadIdx.x;
    const int m0 = blockIdx.y * 64, n0 = blockIdx.x * 64;
    const int w = tid >> 6, lane = tid & 63;
    const int wm = (w >> 1) * 32, wn = (w & 1) * 32;
    const int quad = lane >> 4, l15 = lane & 15;
    const int lrow = tid >> 2;        // 0..63
    const int lcol = (tid & 3) * 8;   // 0,8,16,24

    f32x4 acc[2][2] = {};

    for (int k0 = 0; k0 < K; k0 += 32) {
        uint4 av = *(const uint4*)(A  + (long long)(m0 + lrow) * K + k0 + lcol);
        uint4 bv = *(const uint4*)(BT + (long long)(n0 + lrow) * ldb + k0 + lcol);
        __syncthreads();
        *(uint4*)(As + lrow * 32 + lcol) = av;
        *(uint4*)(Bs + lrow * 32 + lcol) = bv;
        __syncthreads();
        bf16x8 a0 = *(const bf16x8*)(As + (wm +  0 + l15) * 32 + quad * 8);
        bf16x8 a1 = *(const bf16x8*)(As + (wm + 16 + l15) * 32 + quad * 8);
        bf16x8 b0 = *(const bf16x8*)(Bs + (wn +  0 + l15) * 32 + quad * 8);
        bf16x8 b1 = *(const bf16x8*)(Bs + (wn + 16 + l15) * 32 + quad * 8);
        acc[0][0] = __builtin_amdgcn_mfma_f32_16x16x32_bf16(a0, b0, acc[0][0], 0, 0, 0);
        acc[0][1] = __builtin_amdgcn_mfma_f32_16x16x32_bf16(a0, b1, acc[0][1], 0, 0, 0);
        acc[1][0] = __builtin_amdgcn_mfma_f32_16x16x32_bf16(a1, b0, acc[1][0], 0, 0, 0);
        acc[1][1] = __builtin_amdgcn_mfma_f32_16x16x32_bf16(a1, b1, acc[1][1], 0, 0, 0);
    }

    const int r0 = quad * 4;
    #pragma unroll
    for (int i = 0; i < 2; i++) {
        #pragma unroll
        for (int j = 0; j < 2; j++) {
            int gn = n0 + wn + j * 16 + l15;
            float bv = bias ? bias[gn] : 0.0f;
            #pragma unroll
            for (int r = 0; r < 4; r++) {
                int gm = m0 + wm + i * 16 + r0 + r;
                float v = acc[i][j][r] + bv;
                if (epi == 1) {
                    float x3 = v * v * v;
                    v = 0.5f * v * (1.0f + tanhf(0.7978845608028654f * (v + 0.044715f * x3)));
                }
                long long off = (long long)gm * N + gn;
                if (accumF) v += outF[off];
                if (residB) v += b2f(residB[off]);
                if (outF) outF[off] = v;
                if (outB) outB[off] = f2b(v);
            }
        }
    }
}

// ---------- windowed attention: one block per (b, window, head), 52 KB LDS ----------
__global__ __launch_bounds__(256) void attn_kernel(const unsigned short* __restrict__ qkv,
                                                   unsigned short* __restrict__ o) {
    __shared__ float qs[64 * 65], ks[64 * 65], vs[64 * 65];  // qs reused for scores
    __shared__ float pmax[4 * 64], psum[4 * 64];
    int blk = blockIdx.x;                 // b*16*12 + w*12 + h
    int h = blk % 12;
    int bw = blk / 12;
    int wi = bw % 16, b = bw / 16;
    int rowBase = b * 1024 + wi * 64;
    int tid = threadIdx.x;

    int lr = tid >> 2, c0 = (tid & 3) * 16;
    const unsigned short* src = qkv + (long long)(rowBase + lr) * 2304 + h * 64 + c0;
    #pragma unroll
    for (int j = 0; j < 16; j++) {
        qs[lr * 65 + c0 + j] = b2f(src[j]);
        ks[lr * 65 + c0 + j] = b2f(src[768 + j]);
        vs[lr * 65 + c0 + j] = b2f(src[1536 + j]);
    }
    __syncthreads();

    int r = tid & 63, cg = tid >> 6;
    float svals[16];
    float smax = -1e30f;
    #pragma unroll
    for (int j = 0; j < 16; j++) {
        int c = cg * 16 + j;
        float acc = 0.0f;
        for (int kk = 0; kk < 64; kk++) acc += qs[r * 65 + kk] * ks[c * 65 + kk];
        acc *= 0.125f;
        svals[j] = acc;
        smax = fmaxf(smax, acc);
    }
    pmax[cg * 64 + r] = smax;
    __syncthreads();   // all qs reads done; qs reusable as score buffer
    float m = fmaxf(fmaxf(pmax[r], pmax[64 + r]), fmaxf(pmax[128 + r], pmax[192 + r]));
    float lsum = 0.0f;
    #pragma unroll
    for (int j = 0; j < 16; j++) {
        float e = __expf(svals[j] - m);
        qs[r * 65 + cg * 16 + j] = e;
        lsum += e;
    }
    psum[cg * 64 + r] = lsum;
    __syncthreads();
    float inv = 1.0f / (psum[r] + psum[64 + r] + psum[128 + r] + psum[192 + r]);

    unsigned short ov[16];
    #pragma unroll
    for (int j = 0; j < 16; j++) {
        int d = cg * 16 + j;
        float acc = 0.0f;
        for (int c = 0; c < 64; c++) acc += qs[r * 65 + c] * vs[c * 65 + d];
        ov[j] = f2b(acc * inv);
    }
    unsigned short* dst = o + (long long)(rowBase + r) * 768 + h * 64 + cg * 16;
    #pragma unroll
    for (int j = 0; j < 16; j++) dst[j] = ov[j];
}

extern "C" void kernel_launch(void* const* d_in, const int* in_sizes, int n_in,
                              void* d_out, int out_size, void* d_ws, size_t ws_size,
                              hipStream_t stream) {
    const float* input   = (const float*)d_in[0];
    const float* patch_w = (const float*)d_in[1];
    const float* patch_b = (const float*)d_in[2];
    const float* ln_g    = (const float*)d_in[3];
    const float* ln_b    = (const float*)d_in[4];
    const float* qkv_w   = (const float*)d_in[5];
    const float* qkv_b   = (const float*)d_in[6];
    const float* proj_w  = (const float*)d_in[7];
    const float* proj_b  = (const float*)d_in[8];
    const float* ff1_w   = (const float*)d_in[9];
    const float* ff1_b   = (const float*)d_in[10];
    const float* ff2_w   = (const float*)d_in[11];
    const float* ff2_b   = (const float*)d_in[12];
    float* out = (float*)d_out;

    const int MN = 16384;   // B*N tokens
    const int D = 768, F = 3072, TD = 2304;

    // ---- workspace layout: 83,165,184 uint16 = 166.3 MB total ----
    unsigned short* wPatch = (unsigned short*)d_ws;            // 589824
    unsigned short* wQkvT  = wPatch + 589824;                  // 1769472   (2304,768)
    unsigned short* wProjT = wQkvT + 1769472;                  // 589824    (768,768)
    unsigned short* wFf1T  = wProjT + 589824;                  // 2359296   (3072,768)
    unsigned short* wFf2T  = wFf1T + 2359296;                  // 2359296   (768,3072)
    unsigned short* qkvBuf = wFf2T + 2359296;                  // 37748736  (16384,2304)
    unsigned short* xid    = qkvBuf + 37748736;                // 12582912  identity / x2 bf16
    unsigned short* t0     = xid + 12582912;                   // 12582912  y / o bf16
    unsigned short* t1     = t0 + 12582912;                    // 12582912  im2col / h-chunk
    // d_out (f32, 16384x768) doubles as scratch: xe -> y_f32 -> x2_f32 -> final

    // ---- weight prep ----
    convert_bf16_kernel<<<(589824 + 255) / 256, 256, 0, stream>>>(patch_w, wPatch, 589824);
    transpose_to_bf16_kernel<<<(1769472 + 255) / 256, 256, 0, stream>>>(qkv_w, wQkvT, D, TD);
    transpose_to_bf16_kernel<<<(589824 + 255) / 256, 256, 0, stream>>>(proj_w, wProjT, D, D);
    transpose_to_bf16_kernel<<<(2359296 + 255) / 256, 256, 0, stream>>>(ff1_w, wFf1T, D, F);
    transpose_to_bf16_kernel<<<(2359296 + 255) / 256, 256, 0, stream>>>(ff2_w, wFf2T, F, D);

    // ---- pipeline ----
    im2col_kernel<<<(MN * 768) / 256, 256, 0, stream>>>(input, t1);

    // G1: xe = im2col @ patch_w^T + patch_b  -> d_out (f32)
    gemm_bt_kernel<<<dim3(D / 64, MN / 64), 256, 0, stream>>>(t1, wPatch, patch_b, nullptr,
                                                              out, nullptr, MN, D, 768, 768, 0, 0);
    // LN + PE -> xid (bf16 identity + GEMM input)
    ln_pe_kernel<<<MN, 256, 0, stream>>>(out, ln_g, ln_b, xid);

    // FF#1, chunked over F in 4 slices of 768; y accumulates in d_out (f32)
    for (int c = 0; c < 4; c++) {
        // h_c = gelu(xid @ ff1_c + b1_c) -> t1 (bf16)
        gemm_bt_kernel<<<dim3(768 / 64, MN / 64), 256, 0, stream>>>(
            xid, wFf1T + (long long)c * 768 * 768, ff1_b + c * 768, nullptr,
            nullptr, t1, MN, 768, 768, 768, 1, 0);
        // y (+)= h_c @ ff2_c (+ b2 on c==0); final chunk also emits y bf16 -> t0
        gemm_bt_kernel<<<dim3(D / 64, MN / 64), 256, 0, stream>>>(
            t1, wFf2T + c * 768, (c == 0) ? ff2_b : nullptr, nullptr,
            out, (c == 3) ? t0 : nullptr, MN, D, 768, 3072, 0, c > 0 ? 1 : 0);
    }

    // G4: qkv = y @ qkv_w + qkv_b -> qkvBuf (bf16)
    gemm_bt_kernel<<<dim3(TD / 64, MN / 64), 256, 0, stream>>>(t0, wQkvT, qkv_b, nullptr,
                                                               nullptr, qkvBuf, MN, TD, 768, 768, 0, 0);
    // attention -> o (bf16) into t0
    attn_kernel<<<16 * 16 * 12, 256, 0, stream>>>(qkvBuf, t0);

    // G6: x2 = o @ proj + proj_b + xid  -> d_out (f32) + xid (bf16, overwrites identity)
    gemm_bt_kernel<<<dim3(D / 64, MN / 64), 256, 0, stream>>>(t0, wProjT, proj_b, xid,
                                                              out, xid, MN, D, 768, 768, 0, 0);

    // FF#2, chunked; accumulate into d_out (which holds x2 = the residual)
    for (int c = 0; c < 4; c++) {
        gemm_bt_kernel<<<dim3(768 / 64, MN / 64), 256, 0, stream>>>(
            xid, wFf1T + (long long)c * 768 * 768, ff1_b + c * 768, nullptr,
            nullptr, t1, MN, 768, 768, 768, 1, 0);
        gemm_bt_kernel<<<dim3(D / 64, MN / 64), 256, 0, stream>>>(
            t1, wFf2T + c * 768, (c == 0) ? ff2_b : nullptr, nullptr,
            out, nullptr, MN, D, 768, 3072, 0, 1);
    }
}

// Round 3
// 1057.816 us; speedup vs baseline: 1.4479x; 1.4479x over previous
//
#include <hip/hip_runtime.h>

typedef unsigned int uint;
typedef short bf16x8 __attribute__((ext_vector_type(8)));
typedef float f32x4 __attribute__((ext_vector_type(4)));

// ---------- bf16 helpers (bit-level, RNE) ----------
__device__ __forceinline__ unsigned short f2b(float f) {
    uint u = __builtin_bit_cast(uint, f);
    u += 0x7fffu + ((u >> 16) & 1u);
    return (unsigned short)(u >> 16);
}
__device__ __forceinline__ float b2f(unsigned short h) {
    uint u = ((uint)h) << 16;
    return __builtin_bit_cast(float, u);
}

// ---------- async global->LDS, 16B per lane (wave-uniform LDS base + lane*16) ----------
__device__ __forceinline__ void gl_lds16(const unsigned short* g, unsigned short* l) {
    __builtin_amdgcn_global_load_lds(
        reinterpret_cast<const __attribute__((address_space(1))) unsigned int*>(
            reinterpret_cast<uintptr_t>(g)),
        reinterpret_cast<__attribute__((address_space(3))) unsigned int*>(
            reinterpret_cast<uintptr_t>(l)),
        16, 0, 0);
}

// ---------- weight prep ----------
__global__ __launch_bounds__(256) void convert_bf16_kernel(const float* __restrict__ src,
                                                           unsigned short* __restrict__ dst, int n) {
    int idx = blockIdx.x * 256 + threadIdx.x;
    if (idx < n) dst[idx] = f2b(src[idx]);
}

// src is (K, N) row-major; dst is (N, K) row-major (i.e. B^T), bf16.
__global__ __launch_bounds__(256) void transpose_to_bf16_kernel(const float* __restrict__ src,
                                                                unsigned short* __restrict__ dst,
                                                                int K, int N) {
    long long idx = (long long)blockIdx.x * 256 + threadIdx.x;
    if (idx >= (long long)K * N) return;
    int k = (int)(idx / N);
    int n = (int)(idx % N);
    dst[(long long)n * K + k] = f2b(src[idx]);
}

// ---------- im2col: input (B,C,H,W) -> A (16384, 768) bf16, k = c*256+p*16+q ----------
__global__ __launch_bounds__(256) void im2col_kernel(const float* __restrict__ in,
                                                     unsigned short* __restrict__ out) {
    long long idx = (long long)blockIdx.x * 256 + threadIdx.x; // < 16384*768
    int k = (int)(idx % 768);
    int n = (int)(idx / 768);
    int b = n >> 10, t = n & 1023;
    int hp = t >> 5, wp = t & 31;
    int c = k >> 8, rm = k & 255;
    int p = rm >> 4, q = rm & 15;
    long long src = (((long long)(b * 3 + c) * 512) + hp * 16 + p) * 512 + wp * 16 + q;
    out[idx] = f2b(in[src]);
}

// ---------- LayerNorm + sinusoidal PE -> bf16 ----------
__global__ __launch_bounds__(256) void ln_pe_kernel(const float* __restrict__ xe,
                                                    const float* __restrict__ g,
                                                    const float* __restrict__ bb,
                                                    unsigned short* __restrict__ xb) {
    int row = blockIdx.x;            // 0..16383
    int pos = row & 1023;
    const float* xr = xe + (long long)row * 768;
    float v0 = xr[threadIdx.x];
    float v1 = xr[threadIdx.x + 256];
    float v2 = xr[threadIdx.x + 512];
    float s = v0 + v1 + v2;
    float sq = v0 * v0 + v1 * v1 + v2 * v2;
    for (int o = 32; o > 0; o >>= 1) {
        s  += __shfl_down(s, o, 64);
        sq += __shfl_down(sq, o, 64);
    }
    __shared__ float ps[4], pq[4];
    int w = threadIdx.x >> 6, lane = threadIdx.x & 63;
    if (lane == 0) { ps[w] = s; pq[w] = sq; }
    __syncthreads();
    float ts = ps[0] + ps[1] + ps[2] + ps[3];
    float tq = pq[0] + pq[1] + pq[2] + pq[3];
    float mean = ts * (1.0f / 768.0f);
    float var  = tq * (1.0f / 768.0f) - mean * mean;
    float inv  = rsqrtf(var + 1e-5f);
    #pragma unroll
    for (int dd = 0; dd < 3; dd++) {
        int d = threadIdx.x + dd * 256;
        float val = (dd == 0) ? v0 : (dd == 1) ? v1 : v2;
        float y = (val - mean) * inv * g[d] + bb[d];
        float freq = __expf(-(float)(d & ~1) * (9.210340371976184f / 768.0f));
        float ang = (float)pos * freq;
        y += (d & 1) ? cosf(ang) : sinf(ang);
        xb[(long long)row * 768 + d] = f2b(y);
    }
}

// ---------- 128x128 bf16 MFMA GEMM (m97 structure): C = A(MxK) * BT(N rows, ldb)^T ----------
// epilogue: v = acc (+ bias[gn]); epi==1 -> gelu; accumF -> v += outF[off];
// residB -> v += b2f(residB[off]); write outF / outB if non-null.
__global__ __launch_bounds__(256) void gemm128_kernel(const unsigned short* __restrict__ A,
                                                      const unsigned short* __restrict__ BT,
                                                      const float* __restrict__ bias,
                                                      const unsigned short* __restrict__ residB,
                                                      float* __restrict__ outF,
                                                      unsigned short* __restrict__ outB,
                                                      int M, int N, int K, int ldb,
                                                      int epi, int accumF) {
    __shared__ unsigned short As[128 * 32];   // 8 KB, row-major contiguous (NO padding)
    __shared__ unsigned short Bs[128 * 32];
    const int tid = threadIdx.x;
    const int m0 = blockIdx.y * 128, n0 = blockIdx.x * 128;
    const int w = tid >> 6, lane = tid & 63;
    const int wm = (w >> 1) * 64, wn = (w & 1) * 64;   // 2x2 wave grid, 64x64 each
    const int quad = lane >> 4, l15 = lane & 15;

    // staging: thread t covers row t>>2 (0..63) and rows +64, col (t&3)*8 (16B each)
    const int srow = tid >> 2;
    const int scol = (tid & 3) * 8;
    const unsigned short* Ag0 = A  + (long long)(m0 + srow) * K + scol;
    const unsigned short* Ag1 = Ag0 + (long long)64 * K;
    const unsigned short* Bg0 = BT + (long long)(n0 + srow) * ldb + scol;
    const unsigned short* Bg1 = Bg0 + (long long)64 * ldb;
    unsigned short* Ad0 = As + srow * 32 + scol;
    unsigned short* Ad1 = Ad0 + 64 * 32;
    unsigned short* Bd0 = Bs + srow * 32 + scol;
    unsigned short* Bd1 = Bd0 + 64 * 32;

    f32x4 acc[4][4] = {};

    for (int k0 = 0; k0 < K; k0 += 32) {
        __syncthreads();                 // previous iter's LDS reads complete
        gl_lds16(Ag0 + k0, Ad0);
        gl_lds16(Ag1 + k0, Ad1);
        gl_lds16(Bg0 + k0, Bd0);
        gl_lds16(Bg1 + k0, Bd1);
        __syncthreads();                 // drains vmcnt(0): staged data visible

        bf16x8 af[4], bfr[4];
        #pragma unroll
        for (int i = 0; i < 4; i++)
            af[i] = *(const bf16x8*)(As + (wm + i * 16 + l15) * 32 + quad * 8);
        #pragma unroll
        for (int j = 0; j < 4; j++)
            bfr[j] = *(const bf16x8*)(Bs + (wn + j * 16 + l15) * 32 + quad * 8);
        #pragma unroll
        for (int i = 0; i < 4; i++)
            #pragma unroll
            for (int j = 0; j < 4; j++)
                acc[i][j] = __builtin_amdgcn_mfma_f32_16x16x32_bf16(af[i], bfr[j], acc[i][j], 0, 0, 0);
    }

    const int r0 = quad * 4;
    #pragma unroll
    for (int i = 0; i < 4; i++) {
        #pragma unroll
        for (int j = 0; j < 4; j++) {
            int gn = n0 + wn + j * 16 + l15;
            float bv = bias ? bias[gn] : 0.0f;
            #pragma unroll
            for (int r = 0; r < 4; r++) {
                int gm = m0 + wm + i * 16 + r0 + r;
                float v = acc[i][j][r] + bv;
                if (epi == 1) {
                    float t = 0.7978845608028654f * (v + 0.044715f * v * v * v);
                    v = v / (1.0f + __expf(-2.0f * t));   // == 0.5v(1+tanh(t))
                }
                long long off = (long long)gm * N + gn;
                if (accumF) v += outF[off];
                if (residB) v += b2f(residB[off]);
                if (outF) outF[off] = v;
                if (outB) outB[off] = f2b(v);
            }
        }
    }
}

// ---------- windowed attention: one block per (b, window, head), 52 KB LDS ----------
__global__ __launch_bounds__(256) void attn_kernel(const unsigned short* __restrict__ qkv,
                                                   unsigned short* __restrict__ o) {
    __shared__ float qs[64 * 65], ks[64 * 65], vs[64 * 65];  // qs reused for probs
    __shared__ float pmax[4 * 64], psum[4 * 64];
    int blk = blockIdx.x;                 // b*16*12 + w*12 + h
    int h = blk % 12;
    int bw = blk / 12;
    int wi = bw % 16, b = bw / 16;
    int rowBase = b * 1024 + wi * 64;
    int tid = threadIdx.x;

    int lr = tid >> 2, c0 = (tid & 3) * 16;
    const unsigned short* src = qkv + (long long)(rowBase + lr) * 2304 + h * 64 + c0;
    #pragma unroll
    for (int j = 0; j < 16; j++) {
        qs[lr * 65 + c0 + j] = b2f(src[j]);
        ks[lr * 65 + c0 + j] = b2f(src[768 + j]);
        vs[lr * 65 + c0 + j] = b2f(src[1536 + j]);
    }
    __syncthreads();

    int r = tid & 63, cg = tid >> 6;
    float svals[16] = {};
    for (int kk = 0; kk < 64; kk++) {
        float qv = qs[r * 65 + kk];                    // per-lane, 2-way bank alias (free)
        #pragma unroll
        for (int j = 0; j < 16; j++)
            svals[j] += qv * ks[(cg * 16 + j) * 65 + kk];   // wave-uniform broadcast
    }
    float smax = -1e30f;
    #pragma unroll
    for (int j = 0; j < 16; j++) {
        svals[j] *= 0.125f;
        smax = fmaxf(smax, svals[j]);
    }
    pmax[cg * 64 + r] = smax;
    __syncthreads();   // all qs(Q) reads done; qs reusable as prob buffer
    float m = fmaxf(fmaxf(pmax[r], pmax[64 + r]), fmaxf(pmax[128 + r], pmax[192 + r]));
    float lsum = 0.0f;
    #pragma unroll
    for (int j = 0; j < 16; j++) {
        float e = __expf(svals[j] - m);
        qs[r * 65 + cg * 16 + j] = e;
        lsum += e;
    }
    psum[cg * 64 + r] = lsum;
    __syncthreads();
    float inv = 1.0f / (psum[r] + psum[64 + r] + psum[128 + r] + psum[192 + r]);

    float oacc[16] = {};
    for (int c = 0; c < 64; c++) {
        float pv = qs[r * 65 + c];
        #pragma unroll
        for (int j = 0; j < 16; j++)
            oacc[j] += pv * vs[c * 65 + cg * 16 + j];       // wave-uniform broadcast
    }
    unsigned short* dst = o + (long long)(rowBase + r) * 768 + h * 64 + cg * 16;
    #pragma unroll
    for (int j = 0; j < 16; j++) dst[j] = f2b(oacc[j] * inv);
}

extern "C" void kernel_launch(void* const* d_in, const int* in_sizes, int n_in,
                              void* d_out, int out_size, void* d_ws, size_t ws_size,
                              hipStream_t stream) {
    const float* input   = (const float*)d_in[0];
    const float* patch_w = (const float*)d_in[1];
    const float* patch_b = (const float*)d_in[2];
    const float* ln_g    = (const float*)d_in[3];
    const float* ln_b    = (const float*)d_in[4];
    const float* qkv_w   = (const float*)d_in[5];
    const float* qkv_b   = (const float*)d_in[6];
    const float* proj_w  = (const float*)d_in[7];
    const float* proj_b  = (const float*)d_in[8];
    const float* ff1_w   = (const float*)d_in[9];
    const float* ff1_b   = (const float*)d_in[10];
    const float* ff2_w   = (const float*)d_in[11];
    const float* ff2_b   = (const float*)d_in[12];
    float* out = (float*)d_out;

    const int MN = 16384;   // B*N tokens
    const int D = 768, F = 3072, TD = 2304;

    // ---- workspace layout: 83,165,184 uint16 = 166.33 MB (proven to fit) ----
    unsigned short* wPatch = (unsigned short*)d_ws;            // (768,768)
    unsigned short* wQkvT  = wPatch + 589824;                  // (2304,768)
    unsigned short* wProjT = wQkvT + 1769472;                  // (768,768)
    unsigned short* wFf1T  = wProjT + 589824;                  // (3072,768)
    unsigned short* wFf2T  = wFf1T + 2359296;                  // (768,3072)
    unsigned short* bigBuf = wFf2T + 2359296;                  // 50331648: im2col -> h -> qkv -> h2
    unsigned short* xid    = bigBuf + 50331648;                // 12582912: identity / x2 bf16
    unsigned short* t0     = xid + 12582912;                   // 12582912: y / o bf16
    // d_out (f32, 16384x768) doubles as scratch: xe -> y_f32 -> x2_f32 -> final

    // ---- weight prep ----
    convert_bf16_kernel<<<(589824 + 255) / 256, 256, 0, stream>>>(patch_w, wPatch, 589824);
    transpose_to_bf16_kernel<<<(1769472 + 255) / 256, 256, 0, stream>>>(qkv_w, wQkvT, D, TD);
    transpose_to_bf16_kernel<<<(589824 + 255) / 256, 256, 0, stream>>>(proj_w, wProjT, D, D);
    transpose_to_bf16_kernel<<<(2359296 + 255) / 256, 256, 0, stream>>>(ff1_w, wFf1T, D, F);
    transpose_to_bf16_kernel<<<(2359296 + 255) / 256, 256, 0, stream>>>(ff2_w, wFf2T, F, D);

    // ---- pipeline ----
    im2col_kernel<<<(MN * 768) / 256, 256, 0, stream>>>(input, bigBuf);

    // G1: xe = im2col @ patch_w^T + patch_b  -> d_out (f32)
    gemm128_kernel<<<dim3(D / 128, MN / 128), 256, 0, stream>>>(bigBuf, wPatch, patch_b, nullptr,
                                                                out, nullptr, MN, D, 768, 768, 0, 0);
    // LN + PE -> xid (bf16 identity + GEMM input)
    ln_pe_kernel<<<MN, 256, 0, stream>>>(out, ln_g, ln_b, xid);

    // FF#1 unchunked: h = gelu(xid @ ff1 + b1) -> bigBuf (bf16, 100.7 MB)
    gemm128_kernel<<<dim3(F / 128, MN / 128), 256, 0, stream>>>(xid, wFf1T, ff1_b, nullptr,
                                                                nullptr, bigBuf, MN, F, 768, 768, 1, 0);
    // y = h @ ff2 + b2 -> d_out (f32) + t0 (bf16)
    gemm128_kernel<<<dim3(D / 128, MN / 128), 256, 0, stream>>>(bigBuf, wFf2T, ff2_b, nullptr,
                                                                out, t0, MN, D, F, F, 0, 0);
    // qkv = y @ qkv_w + qkv_b -> bigBuf (bf16, 75.5 MB; h dead)
    gemm128_kernel<<<dim3(TD / 128, MN / 128), 256, 0, stream>>>(t0, wQkvT, qkv_b, nullptr,
                                                                 nullptr, bigBuf, MN, TD, 768, 768, 0, 0);
    // attention -> o (bf16) into t0
    attn_kernel<<<16 * 16 * 12, 256, 0, stream>>>(bigBuf, t0);

    // x2 = o @ proj + proj_b + xid -> d_out (f32) + xid (bf16, overwrites identity)
    gemm128_kernel<<<dim3(D / 128, MN / 128), 256, 0, stream>>>(t0, wProjT, proj_b, xid,
                                                                out, xid, MN, D, 768, 768, 0, 0);

    // FF#2 unchunked: h2 = gelu(x2 @ ff1 + b1) -> bigBuf (qkv dead)
    gemm128_kernel<<<dim3(F / 128, MN / 128), 256, 0, stream>>>(xid, wFf1T, ff1_b, nullptr,
                                                                nullptr, bigBuf, MN, F, 768, 768, 1, 0);
    // out = h2 @ ff2 + b2 + x2  (accumulate into d_out which holds x2)
    gemm128_kernel<<<dim3(D / 128, MN / 128), 256, 0, stream>>>(bigBuf, wFf2T, ff2_b, nullptr,
                                                                out, nullptr, MN, D, F, F, 0, 1);
}

// Round 4
// 964.681 us; speedup vs baseline: 1.5877x; 1.0965x over previous
//
#include <hip/hip_runtime.h>

typedef unsigned int uint;
typedef short bf16x8 __attribute__((ext_vector_type(8)));
typedef float f32x4 __attribute__((ext_vector_type(4)));

// ---------- bf16 helpers (bit-level, RNE) ----------
__device__ __forceinline__ unsigned short f2b(float f) {
    uint u = __builtin_bit_cast(uint, f);
    u += 0x7fffu + ((u >> 16) & 1u);
    return (unsigned short)(u >> 16);
}
__device__ __forceinline__ float b2f(unsigned short h) {
    uint u = ((uint)h) << 16;
    return __builtin_bit_cast(float, u);
}

// ---------- fast tanh-gelu: v * sigmoid(1.5957691*(v+0.044715 v^3)) ----------
// exp(-1.5957691*t2) via __expf (v_exp_f32), reciprocal via v_rcp_f32.
__device__ __forceinline__ float fast_gelu(float v) {
    float s  = v * v;
    float t2 = __builtin_fmaf(0.044715f * s, v, v);     // v + 0.044715 v^3
    float e  = __expf(-1.5957691216f * t2);             // exp(-2*0.79788456*t2)
    return v * __builtin_amdgcn_rcpf(1.0f + e);
}

// ---------- async global->LDS, 16B per lane (wave-uniform LDS base + lane*16) ----------
__device__ __forceinline__ void gl_lds16(const unsigned short* g, unsigned short* l) {
    __builtin_amdgcn_global_load_lds(
        reinterpret_cast<const __attribute__((address_space(1))) unsigned int*>(
            reinterpret_cast<uintptr_t>(g)),
        reinterpret_cast<__attribute__((address_space(3))) unsigned int*>(
            reinterpret_cast<uintptr_t>(l)),
        16, 0, 0);
}

// ---------- weight prep ----------
__global__ __launch_bounds__(256) void convert_bf16_kernel(const float* __restrict__ src,
                                                           unsigned short* __restrict__ dst, int n) {
    int idx = blockIdx.x * 256 + threadIdx.x;
    if (idx < n) dst[idx] = f2b(src[idx]);
}

// src is (K, N) row-major; dst is (N, K) row-major (i.e. B^T), bf16.
__global__ __launch_bounds__(256) void transpose_to_bf16_kernel(const float* __restrict__ src,
                                                                unsigned short* __restrict__ dst,
                                                                int K, int N) {
    long long idx = (long long)blockIdx.x * 256 + threadIdx.x;
    if (idx >= (long long)K * N) return;
    int k = (int)(idx / N);
    int n = (int)(idx % N);
    dst[(long long)n * K + k] = f2b(src[idx]);
}

// ---------- im2col: input (B,C,H,W) -> A (16384, 768) bf16, k = c*256+p*16+q ----------
__global__ __launch_bounds__(256) void im2col_kernel(const float* __restrict__ in,
                                                     unsigned short* __restrict__ out) {
    long long idx = (long long)blockIdx.x * 256 + threadIdx.x; // < 16384*768
    int k = (int)(idx % 768);
    int n = (int)(idx / 768);
    int b = n >> 10, t = n & 1023;
    int hp = t >> 5, wp = t & 31;
    int c = k >> 8, rm = k & 255;
    int p = rm >> 4, q = rm & 15;
    long long src = (((long long)(b * 3 + c) * 512) + hp * 16 + p) * 512 + wp * 16 + q;
    out[idx] = f2b(in[src]);
}

// ---------- LayerNorm + sinusoidal PE -> bf16 ----------
__global__ __launch_bounds__(256) void ln_pe_kernel(const float* __restrict__ xe,
                                                    const float* __restrict__ g,
                                                    const float* __restrict__ bb,
                                                    unsigned short* __restrict__ xb) {
    int row = blockIdx.x;            // 0..16383
    int pos = row & 1023;
    const float* xr = xe + (long long)row * 768;
    float v0 = xr[threadIdx.x];
    float v1 = xr[threadIdx.x + 256];
    float v2 = xr[threadIdx.x + 512];
    float s = v0 + v1 + v2;
    float sq = v0 * v0 + v1 * v1 + v2 * v2;
    for (int o = 32; o > 0; o >>= 1) {
        s  += __shfl_down(s, o, 64);
        sq += __shfl_down(sq, o, 64);
    }
    __shared__ float ps[4], pq[4];
    int w = threadIdx.x >> 6, lane = threadIdx.x & 63;
    if (lane == 0) { ps[w] = s; pq[w] = sq; }
    __syncthreads();
    float ts = ps[0] + ps[1] + ps[2] + ps[3];
    float tq = pq[0] + pq[1] + pq[2] + pq[3];
    float mean = ts * (1.0f / 768.0f);
    float var  = tq * (1.0f / 768.0f) - mean * mean;
    float inv  = rsqrtf(var + 1e-5f);
    #pragma unroll
    for (int dd = 0; dd < 3; dd++) {
        int d = threadIdx.x + dd * 256;
        float val = (dd == 0) ? v0 : (dd == 1) ? v1 : v2;
        float y = (val - mean) * inv * g[d] + bb[d];
        float freq = __expf(-(float)(d & ~1) * (9.210340371976184f / 768.0f));
        float ang = (float)pos * freq;
        y += (d & 1) ? cosf(ang) : sinf(ang);
        xb[(long long)row * 768 + d] = f2b(y);
    }
}

// ---------- 128x128 bf16 MFMA GEMM (m97 structure), XCD-swizzled 1-D grid ----------
// grid = nX * (M/128) blocks; rows striped across XCDs so the nX col-blocks
// sharing an A row-tile run consecutively on ONE XCD (A-tile stays in its L2).
// epilogue: v = acc (+ bias[gn]); epi==1 -> gelu; accumF -> v += outF[off];
// residB -> v += b2f(residB[off]); write outF / outB if non-null.
__global__ __launch_bounds__(256) void gemm128_kernel(const unsigned short* __restrict__ A,
                                                      const unsigned short* __restrict__ BT,
                                                      const float* __restrict__ bias,
                                                      const unsigned short* __restrict__ residB,
                                                      float* __restrict__ outF,
                                                      unsigned short* __restrict__ outB,
                                                      int M, int N, int K, int ldb,
                                                      int epi, int accumF) {
    __shared__ unsigned short As[128 * 32];   // 8 KB, row-major contiguous (NO padding)
    __shared__ unsigned short Bs[128 * 32];

    // ---- XCD swizzle: id = 8*s + xcd; same row-tile's col-blocks consecutive per XCD
    const int nX = N >> 7;                    // N/128
    int id = blockIdx.x;
    int xcd = id & 7;
    int sq_ = id >> 3;
    int bx = sq_ % nX;
    int by = (sq_ / nX) * 8 + xcd;            // requires (M/128) % 8 == 0

    const int tid = threadIdx.x;
    const int m0 = by * 128, n0 = bx * 128;
    const int w = tid >> 6, lane = tid & 63;
    const int wm = (w >> 1) * 64, wn = (w & 1) * 64;   // 2x2 wave grid, 64x64 each
    const int quad = lane >> 4, l15 = lane & 15;

    // staging: thread t covers row t>>2 (0..63) and rows +64, col (t&3)*8 (16B each)
    const int srow = tid >> 2;
    const int scol = (tid & 3) * 8;
    const unsigned short* Ag0 = A  + (long long)(m0 + srow) * K + scol;
    const unsigned short* Ag1 = Ag0 + (long long)64 * K;
    const unsigned short* Bg0 = BT + (long long)(n0 + srow) * ldb + scol;
    const unsigned short* Bg1 = Bg0 + (long long)64 * ldb;
    unsigned short* Ad0 = As + srow * 32 + scol;
    unsigned short* Ad1 = Ad0 + 64 * 32;
    unsigned short* Bd0 = Bs + srow * 32 + scol;
    unsigned short* Bd1 = Bd0 + 64 * 32;

    f32x4 acc[4][4] = {};

    for (int k0 = 0; k0 < K; k0 += 32) {
        __syncthreads();                 // previous iter's LDS reads complete
        gl_lds16(Ag0 + k0, Ad0);
        gl_lds16(Ag1 + k0, Ad1);
        gl_lds16(Bg0 + k0, Bd0);
        gl_lds16(Bg1 + k0, Bd1);
        __syncthreads();                 // drains vmcnt(0): staged data visible

        bf16x8 af[4], bfr[4];
        #pragma unroll
        for (int i = 0; i < 4; i++)
            af[i] = *(const bf16x8*)(As + (wm + i * 16 + l15) * 32 + quad * 8);
        #pragma unroll
        for (int j = 0; j < 4; j++)
            bfr[j] = *(const bf16x8*)(Bs + (wn + j * 16 + l15) * 32 + quad * 8);
        #pragma unroll
        for (int i = 0; i < 4; i++)
            #pragma unroll
            for (int j = 0; j < 4; j++)
                acc[i][j] = __builtin_amdgcn_mfma_f32_16x16x32_bf16(af[i], bfr[j], acc[i][j], 0, 0, 0);
    }

    const int r0 = quad * 4;
    #pragma unroll
    for (int i = 0; i < 4; i++) {
        #pragma unroll
        for (int j = 0; j < 4; j++) {
            int gn = n0 + wn + j * 16 + l15;
            float bv = bias ? bias[gn] : 0.0f;
            #pragma unroll
            for (int r = 0; r < 4; r++) {
                int gm = m0 + wm + i * 16 + r0 + r;
                float v = acc[i][j][r] + bv;
                if (epi == 1) v = fast_gelu(v);
                long long off = (long long)gm * N + gn;
                if (accumF) v += outF[off];
                if (residB) v += b2f(residB[off]);
                if (outF) outF[off] = v;
                if (outB) outB[off] = f2b(v);
            }
        }
    }
}

// ---------- windowed attention: one block per (b, window, head), 52 KB LDS ----------
__global__ __launch_bounds__(256) void attn_kernel(const unsigned short* __restrict__ qkv,
                                                   unsigned short* __restrict__ o) {
    __shared__ float qs[64 * 65], ks[64 * 65], vs[64 * 65];  // qs reused for probs
    __shared__ float pmax[4 * 64], psum[4 * 64];
    int blk = blockIdx.x;                 // b*16*12 + w*12 + h
    int h = blk % 12;
    int bw = blk / 12;
    int wi = bw % 16, b = bw / 16;
    int rowBase = b * 1024 + wi * 64;
    int tid = threadIdx.x;

    int lr = tid >> 2, c0 = (tid & 3) * 16;
    const unsigned short* src = qkv + (long long)(rowBase + lr) * 2304 + h * 64 + c0;
    #pragma unroll
    for (int j = 0; j < 16; j++) {
        qs[lr * 65 + c0 + j] = b2f(src[j]);
        ks[lr * 65 + c0 + j] = b2f(src[768 + j]);
        vs[lr * 65 + c0 + j] = b2f(src[1536 + j]);
    }
    __syncthreads();

    int r = tid & 63, cg = tid >> 6;
    float svals[16] = {};
    for (int kk = 0; kk < 64; kk++) {
        float qv = qs[r * 65 + kk];                    // per-lane, 2-way bank alias (free)
        #pragma unroll
        for (int j = 0; j < 16; j++)
            svals[j] += qv * ks[(cg * 16 + j) * 65 + kk];   // wave-uniform broadcast
    }
    float smax = -1e30f;
    #pragma unroll
    for (int j = 0; j < 16; j++) {
        svals[j] *= 0.125f;
        smax = fmaxf(smax, svals[j]);
    }
    pmax[cg * 64 + r] = smax;
    __syncthreads();   // all qs(Q) reads done; qs reusable as prob buffer
    float m = fmaxf(fmaxf(pmax[r], pmax[64 + r]), fmaxf(pmax[128 + r], pmax[192 + r]));
    float lsum = 0.0f;
    #pragma unroll
    for (int j = 0; j < 16; j++) {
        float e = __expf(svals[j] - m);
        qs[r * 65 + cg * 16 + j] = e;
        lsum += e;
    }
    psum[cg * 64 + r] = lsum;
    __syncthreads();
    float inv = __builtin_amdgcn_rcpf(psum[r] + psum[64 + r] + psum[128 + r] + psum[192 + r]);

    float oacc[16] = {};
    for (int c = 0; c < 64; c++) {
        float pv = qs[r * 65 + c];
        #pragma unroll
        for (int j = 0; j < 16; j++)
            oacc[j] += pv * vs[c * 65 + cg * 16 + j];       // wave-uniform broadcast
    }
    unsigned short* dst = o + (long long)(rowBase + r) * 768 + h * 64 + cg * 16;
    #pragma unroll
    for (int j = 0; j < 16; j++) dst[j] = f2b(oacc[j] * inv);
}

extern "C" void kernel_launch(void* const* d_in, const int* in_sizes, int n_in,
                              void* d_out, int out_size, void* d_ws, size_t ws_size,
                              hipStream_t stream) {
    const float* input   = (const float*)d_in[0];
    const float* patch_w = (const float*)d_in[1];
    const float* patch_b = (const float*)d_in[2];
    const float* ln_g    = (const float*)d_in[3];
    const float* ln_b    = (const float*)d_in[4];
    const float* qkv_w   = (const float*)d_in[5];
    const float* qkv_b   = (const float*)d_in[6];
    const float* proj_w  = (const float*)d_in[7];
    const float* proj_b  = (const float*)d_in[8];
    const float* ff1_w   = (const float*)d_in[9];
    const float* ff1_b   = (const float*)d_in[10];
    const float* ff2_w   = (const float*)d_in[11];
    const float* ff2_b   = (const float*)d_in[12];
    float* out = (float*)d_out;

    const int MN = 16384;   // B*N tokens
    const int D = 768, F = 3072, TD = 2304;
    const int NY = MN / 128;  // 128 row-blocks (divisible by 8)

    // ---- workspace layout: 83,165,184 uint16 = 166.33 MB (proven to fit) ----
    unsigned short* wPatch = (unsigned short*)d_ws;            // (768,768)
    unsigned short* wQkvT  = wPatch + 589824;                  // (2304,768)
    unsigned short* wProjT = wQkvT + 1769472;                  // (768,768)
    unsigned short* wFf1T  = wProjT + 589824;                  // (3072,768)
    unsigned short* wFf2T  = wFf1T + 2359296;                  // (768,3072)
    unsigned short* bigBuf = wFf2T + 2359296;                  // 50331648: im2col -> h -> qkv -> h2
    unsigned short* xid    = bigBuf + 50331648;                // 12582912: identity -> x2 bf16
    unsigned short* t0     = xid + 12582912;                   // 12582912: y / o bf16
    // d_out (f32, 16384x768): xe (patch GEMM -> LN), then final output

    // ---- weight prep ----
    convert_bf16_kernel<<<(589824 + 255) / 256, 256, 0, stream>>>(patch_w, wPatch, 589824);
    transpose_to_bf16_kernel<<<(1769472 + 255) / 256, 256, 0, stream>>>(qkv_w, wQkvT, D, TD);
    transpose_to_bf16_kernel<<<(589824 + 255) / 256, 256, 0, stream>>>(proj_w, wProjT, D, D);
    transpose_to_bf16_kernel<<<(2359296 + 255) / 256, 256, 0, stream>>>(ff1_w, wFf1T, D, F);
    transpose_to_bf16_kernel<<<(2359296 + 255) / 256, 256, 0, stream>>>(ff2_w, wFf2T, F, D);

    // ---- pipeline ----
    im2col_kernel<<<(MN * 768) / 256, 256, 0, stream>>>(input, bigBuf);

    // G1: xe = im2col @ patch_w^T + patch_b  -> d_out (f32)
    gemm128_kernel<<<(D / 128) * NY, 256, 0, stream>>>(bigBuf, wPatch, patch_b, nullptr,
                                                       out, nullptr, MN, D, 768, 768, 0, 0);
    // LN + PE -> xid (bf16 identity + GEMM input)
    ln_pe_kernel<<<MN, 256, 0, stream>>>(out, ln_g, ln_b, xid);

    // FF#1: h = gelu(xid @ ff1 + b1) -> bigBuf (bf16, 100.7 MB)
    gemm128_kernel<<<(F / 128) * NY, 256, 0, stream>>>(xid, wFf1T, ff1_b, nullptr,
                                                       nullptr, bigBuf, MN, F, 768, 768, 1, 0);
    // y = h @ ff2 + b2 -> t0 (bf16 only; f32 copy is dead)
    gemm128_kernel<<<(D / 128) * NY, 256, 0, stream>>>(bigBuf, wFf2T, ff2_b, nullptr,
                                                       nullptr, t0, MN, D, F, F, 0, 0);
    // qkv = y @ qkv_w + qkv_b -> bigBuf (bf16, 75.5 MB; h dead)
    gemm128_kernel<<<(TD / 128) * NY, 256, 0, stream>>>(t0, wQkvT, qkv_b, nullptr,
                                                        nullptr, bigBuf, MN, TD, 768, 768, 0, 0);
    // attention -> o (bf16) into t0
    attn_kernel<<<16 * 16 * 12, 256, 0, stream>>>(bigBuf, t0);

    // x2 = o @ proj + proj_b + identity(xid) -> xid (bf16 only; in-place per-element safe)
    gemm128_kernel<<<(D / 128) * NY, 256, 0, stream>>>(t0, wProjT, proj_b, xid,
                                                       nullptr, xid, MN, D, 768, 768, 0, 0);

    // FF#2: h2 = gelu(x2 @ ff1 + b1) -> bigBuf (qkv dead)
    gemm128_kernel<<<(F / 128) * NY, 256, 0, stream>>>(xid, wFf1T, ff1_b, nullptr,
                                                       nullptr, bigBuf, MN, F, 768, 768, 1, 0);
    // out = h2 @ ff2 + b2 + x2(bf16 resid)  (f32, final)
    gemm128_kernel<<<(D / 128) * NY, 256, 0, stream>>>(bigBuf, wFf2T, ff2_b, xid,
                                                       out, nullptr, MN, D, F, F, 0, 0);
}

// Round 5
// 863.158 us; speedup vs baseline: 1.7744x; 1.1176x over previous
//
#include <hip/hip_runtime.h>

typedef unsigned int uint;
typedef short bf16x8 __attribute__((ext_vector_type(8)));
typedef float f32x4 __attribute__((ext_vector_type(4)));

// ---------- bf16 helpers (bit-level, RNE) ----------
__device__ __forceinline__ unsigned short f2b(float f) {
    uint u = __builtin_bit_cast(uint, f);
    u += 0x7fffu + ((u >> 16) & 1u);
    return (unsigned short)(u >> 16);
}
__device__ __forceinline__ float b2f(unsigned short h) {
    uint u = ((uint)h) << 16;
    return __builtin_bit_cast(float, u);
}

// ---------- fast tanh-gelu ----------
__device__ __forceinline__ float fast_gelu(float v) {
    float s  = v * v;
    float t2 = __builtin_fmaf(0.044715f * s, v, v);     // v + 0.044715 v^3
    float e  = __expf(-1.5957691216f * t2);             // exp(-2*0.79788456*t2)
    return v * __builtin_amdgcn_rcpf(1.0f + e);
}

// ---------- async global->LDS, 16B per lane (wave-uniform LDS base + lane*16) ----------
__device__ __forceinline__ void gl_lds16(const unsigned short* g, unsigned short* l) {
    __builtin_amdgcn_global_load_lds(
        reinterpret_cast<const __attribute__((address_space(1))) unsigned int*>(
            reinterpret_cast<uintptr_t>(g)),
        reinterpret_cast<__attribute__((address_space(3))) unsigned int*>(
            reinterpret_cast<uintptr_t>(l)),
        16, 0, 0);
}

// ---------- weight prep ----------
__global__ __launch_bounds__(256) void convert_bf16_kernel(const float* __restrict__ src,
                                                           unsigned short* __restrict__ dst, int n) {
    int idx = blockIdx.x * 256 + threadIdx.x;
    if (idx < n) dst[idx] = f2b(src[idx]);
}

// src is (K, N) row-major; dst is (N, K) row-major (i.e. B^T), bf16.
__global__ __launch_bounds__(256) void transpose_to_bf16_kernel(const float* __restrict__ src,
                                                                unsigned short* __restrict__ dst,
                                                                int K, int N) {
    long long idx = (long long)blockIdx.x * 256 + threadIdx.x;
    if (idx >= (long long)K * N) return;
    int k = (int)(idx / N);
    int n = (int)(idx % N);
    dst[(long long)n * K + k] = f2b(src[idx]);
}

// ---------- im2col: input (B,C,H,W) -> A (16384, 768) bf16, k = c*256+p*16+q ----------
__global__ __launch_bounds__(256) void im2col_kernel(const float* __restrict__ in,
                                                     unsigned short* __restrict__ out) {
    long long idx = (long long)blockIdx.x * 256 + threadIdx.x; // < 16384*768
    int k = (int)(idx % 768);
    int n = (int)(idx / 768);
    int b = n >> 10, t = n & 1023;
    int hp = t >> 5, wp = t & 31;
    int c = k >> 8, rm = k & 255;
    int p = rm >> 4, q = rm & 15;
    long long src = (((long long)(b * 3 + c) * 512) + hp * 16 + p) * 512 + wp * 16 + q;
    out[idx] = f2b(in[src]);
}

// ---------- LayerNorm + sinusoidal PE -> bf16 ----------
__global__ __launch_bounds__(256) void ln_pe_kernel(const float* __restrict__ xe,
                                                    const float* __restrict__ g,
                                                    const float* __restrict__ bb,
                                                    unsigned short* __restrict__ xb) {
    int row = blockIdx.x;            // 0..16383
    int pos = row & 1023;
    const float* xr = xe + (long long)row * 768;
    float v0 = xr[threadIdx.x];
    float v1 = xr[threadIdx.x + 256];
    float v2 = xr[threadIdx.x + 512];
    float s = v0 + v1 + v2;
    float sq = v0 * v0 + v1 * v1 + v2 * v2;
    for (int o = 32; o > 0; o >>= 1) {
        s  += __shfl_down(s, o, 64);
        sq += __shfl_down(sq, o, 64);
    }
    __shared__ float ps[4], pq[4];
    int w = threadIdx.x >> 6, lane = threadIdx.x & 63;
    if (lane == 0) { ps[w] = s; pq[w] = sq; }
    __syncthreads();
    float ts = ps[0] + ps[1] + ps[2] + ps[3];
    float tq = pq[0] + pq[1] + pq[2] + pq[3];
    float mean = ts * (1.0f / 768.0f);
    float var  = tq * (1.0f / 768.0f) - mean * mean;
    float inv  = rsqrtf(var + 1e-5f);
    #pragma unroll
    for (int dd = 0; dd < 3; dd++) {
        int d = threadIdx.x + dd * 256;
        float val = (dd == 0) ? v0 : (dd == 1) ? v1 : v2;
        float y = (val - mean) * inv * g[d] + bb[d];
        float freq = __expf(-(float)(d & ~1) * (9.210340371976184f / 768.0f));
        float ang = (float)pos * freq;
        y += (d & 1) ? cosf(ang) : sinf(ang);
        xb[(long long)row * 768 + d] = f2b(y);
    }
}

// ---------- 128x128 bf16 MFMA GEMM, BK=64, XOR-swizzled LDS, XCD-swizzled grid ----------
// LDS slot (row, col8') holds global (row, col8' ^ (row&7)) -- swizzle applied on the
// global-fetch side so global_load_lds's fixed lane->LDS mapping still works and
// fragment ds_read_b128s land 2 lanes/bank (free). 32 MFMA per barrier pair.
// epilogue: v = acc (+ bias[gn]); epi==1 -> gelu; accumF -> v += outF[off];
// residB -> v += b2f(residB[off]); write outF / outB if non-null.
__global__ __launch_bounds__(256) void gemm128_kernel(const unsigned short* __restrict__ A,
                                                      const unsigned short* __restrict__ BT,
                                                      const float* __restrict__ bias,
                                                      const unsigned short* __restrict__ residB,
                                                      float* __restrict__ outF,
                                                      unsigned short* __restrict__ outB,
                                                      int M, int N, int K, int ldb,
                                                      int epi, int accumF) {
    __shared__ unsigned short As[128 * 64];   // 16 KB each
    __shared__ unsigned short Bs[128 * 64];

    // ---- XCD swizzle: id = 8*s + xcd; a row-tile's col-blocks run consecutively per XCD
    const int nX = N >> 7;                    // N/128
    int id = blockIdx.x;
    int xcd = id & 7;
    int sq_ = id >> 3;
    int bx = sq_ % nX;
    int by = (sq_ / nX) * 8 + xcd;            // requires (M/128) % 8 == 0

    const int tid = threadIdx.x;
    const int m0 = by * 128, n0 = bx * 128;
    const int w = tid >> 6, lane = tid & 63;
    const int wm = (w >> 1) * 64, wn = (w & 1) * 64;   // 2x2 wave grid, 64x64 each
    const int quad = lane >> 4, l15 = lane & 15;

    // staging: thread t -> LDS slot row (t>>3)+32c, col8 (t&7); fetches global col8^(row&7)
    const int srow = tid >> 3;                // 0..31
    const int sc8  = tid & 7;
    const int gc8  = sc8 ^ (srow & 7);        // (row+32c)&7 == srow&7
    const unsigned short* Ag0 = A  + (long long)(m0 + srow) * K + gc8 * 8;
    const unsigned short* Ag1 = Ag0 + (long long)32 * K;
    const unsigned short* Ag2 = Ag0 + (long long)64 * K;
    const unsigned short* Ag3 = Ag0 + (long long)96 * K;
    const unsigned short* Bg0 = BT + (long long)(n0 + srow) * ldb + gc8 * 8;
    const unsigned short* Bg1 = Bg0 + (long long)32 * ldb;
    const unsigned short* Bg2 = Bg0 + (long long)64 * ldb;
    const unsigned short* Bg3 = Bg0 + (long long)96 * ldb;
    unsigned short* Ad0 = As + srow * 64 + sc8 * 8;
    unsigned short* Ad1 = Ad0 + 32 * 64;
    unsigned short* Ad2 = Ad0 + 64 * 64;
    unsigned short* Ad3 = Ad0 + 96 * 64;
    unsigned short* Bd0 = Bs + srow * 64 + sc8 * 8;
    unsigned short* Bd1 = Bd0 + 32 * 64;
    unsigned short* Bd2 = Bd0 + 64 * 64;
    unsigned short* Bd3 = Bd0 + 96 * 64;

    f32x4 acc[4][4] = {};
    const int swz = l15 & 7;   // fragment-row swizzle key

    for (int k0 = 0; k0 < K; k0 += 64) {
        __syncthreads();                 // previous iter's LDS reads complete
        gl_lds16(Ag0 + k0, Ad0);
        gl_lds16(Ag1 + k0, Ad1);
        gl_lds16(Ag2 + k0, Ad2);
        gl_lds16(Ag3 + k0, Ad3);
        gl_lds16(Bg0 + k0, Bd0);
        gl_lds16(Bg1 + k0, Bd1);
        gl_lds16(Bg2 + k0, Bd2);
        gl_lds16(Bg3 + k0, Bd3);
        __syncthreads();                 // drains vmcnt(0): staged data visible

        #pragma unroll
        for (int h = 0; h < 2; h++) {
            const int c8 = h * 4 + quad;
            bf16x8 af[4], bfr[4];
            #pragma unroll
            for (int i = 0; i < 4; i++)
                af[i] = *(const bf16x8*)(As + (wm + i * 16 + l15) * 64 + ((c8 ^ swz) * 8));
            #pragma unroll
            for (int j = 0; j < 4; j++)
                bfr[j] = *(const bf16x8*)(Bs + (wn + j * 16 + l15) * 64 + ((c8 ^ swz) * 8));
            #pragma unroll
            for (int i = 0; i < 4; i++)
                #pragma unroll
                for (int j = 0; j < 4; j++)
                    acc[i][j] = __builtin_amdgcn_mfma_f32_16x16x32_bf16(af[i], bfr[j], acc[i][j], 0, 0, 0);
        }
    }

    const int r0 = quad * 4;
    #pragma unroll
    for (int i = 0; i < 4; i++) {
        #pragma unroll
        for (int j = 0; j < 4; j++) {
            int gn = n0 + wn + j * 16 + l15;
            float bv = bias ? bias[gn] : 0.0f;
            #pragma unroll
            for (int r = 0; r < 4; r++) {
                int gm = m0 + wm + i * 16 + r0 + r;
                float v = acc[i][j][r] + bv;
                if (epi == 1) v = fast_gelu(v);
                long long off = (long long)gm * N + gn;
                if (accumF) v += outF[off];
                if (residB) v += b2f(residB[off]);
                if (outF) outF[off] = v;
                if (outB) outB[off] = f2b(v);
            }
        }
    }
}

// ---------- windowed attention: one block per (b, window, head), 52 KB LDS ----------
__global__ __launch_bounds__(256) void attn_kernel(const unsigned short* __restrict__ qkv,
                                                   unsigned short* __restrict__ o) {
    __shared__ float qs[64 * 65], ks[64 * 65], vs[64 * 65];  // qs reused for probs
    __shared__ float pmax[4 * 64], psum[4 * 64];
    int blk = blockIdx.x;                 // b*16*12 + w*12 + h
    int h = blk % 12;
    int bw = blk / 12;
    int wi = bw % 16, b = bw / 16;
    int rowBase = b * 1024 + wi * 64;
    int tid = threadIdx.x;

    int lr = tid >> 2, c0 = (tid & 3) * 16;
    const unsigned short* src = qkv + (long long)(rowBase + lr) * 2304 + h * 64 + c0;
    #pragma unroll
    for (int j = 0; j < 16; j++) {
        qs[lr * 65 + c0 + j] = b2f(src[j]);
        ks[lr * 65 + c0 + j] = b2f(src[768 + j]);
        vs[lr * 65 + c0 + j] = b2f(src[1536 + j]);
    }
    __syncthreads();

    int r = tid & 63, cg = tid >> 6;
    float svals[16] = {};
    for (int kk = 0; kk < 64; kk++) {
        float qv = qs[r * 65 + kk];                    // per-lane, 2-way bank alias (free)
        #pragma unroll
        for (int j = 0; j < 16; j++)
            svals[j] += qv * ks[(cg * 16 + j) * 65 + kk];   // wave-uniform broadcast
    }
    float smax = -1e30f;
    #pragma unroll
    for (int j = 0; j < 16; j++) {
        svals[j] *= 0.125f;
        smax = fmaxf(smax, svals[j]);
    }
    pmax[cg * 64 + r] = smax;
    __syncthreads();   // all qs(Q) reads done; qs reusable as prob buffer
    float m = fmaxf(fmaxf(pmax[r], pmax[64 + r]), fmaxf(pmax[128 + r], pmax[192 + r]));
    float lsum = 0.0f;
    #pragma unroll
    for (int j = 0; j < 16; j++) {
        float e = __expf(svals[j] - m);
        qs[r * 65 + cg * 16 + j] = e;
        lsum += e;
    }
    psum[cg * 64 + r] = lsum;
    __syncthreads();
    float inv = __builtin_amdgcn_rcpf(psum[r] + psum[64 + r] + psum[128 + r] + psum[192 + r]);

    float oacc[16] = {};
    for (int c = 0; c < 64; c++) {
        float pv = qs[r * 65 + c];
        #pragma unroll
        for (int j = 0; j < 16; j++)
            oacc[j] += pv * vs[c * 65 + cg * 16 + j];       // wave-uniform broadcast
    }
    unsigned short* dst = o + (long long)(rowBase + r) * 768 + h * 64 + cg * 16;
    #pragma unroll
    for (int j = 0; j < 16; j++) dst[j] = f2b(oacc[j] * inv);
}

extern "C" void kernel_launch(void* const* d_in, const int* in_sizes, int n_in,
                              void* d_out, int out_size, void* d_ws, size_t ws_size,
                              hipStream_t stream) {
    const float* input   = (const float*)d_in[0];
    const float* patch_w = (const float*)d_in[1];
    const float* patch_b = (const float*)d_in[2];
    const float* ln_g    = (const float*)d_in[3];
    const float* ln_b    = (const float*)d_in[4];
    const float* qkv_w   = (const float*)d_in[5];
    const float* qkv_b   = (const float*)d_in[6];
    const float* proj_w  = (const float*)d_in[7];
    const float* proj_b  = (const float*)d_in[8];
    const float* ff1_w   = (const float*)d_in[9];
    const float* ff1_b   = (const float*)d_in[10];
    const float* ff2_w   = (const float*)d_in[11];
    const float* ff2_b   = (const float*)d_in[12];
    float* out = (float*)d_out;

    const int MN = 16384;   // B*N tokens
    const int D = 768, F = 3072, TD = 2304;
    const int NY = MN / 128;  // 128 row-blocks (divisible by 8)

    // ---- workspace layout: 83,165,184 uint16 = 166.33 MB (proven to fit) ----
    unsigned short* wPatch = (unsigned short*)d_ws;            // (768,768)
    unsigned short* wQkvT  = wPatch + 589824;                  // (2304,768)
    unsigned short* wProjT = wQkvT + 1769472;                  // (768,768)
    unsigned short* wFf1T  = wProjT + 589824;                  // (3072,768)
    unsigned short* wFf2T  = wFf1T + 2359296;                  // (768,3072)
    unsigned short* bigBuf = wFf2T + 2359296;                  // 50331648: im2col -> h -> qkv -> h2
    unsigned short* xid    = bigBuf + 50331648;                // 12582912: identity -> x2 bf16
    unsigned short* t0     = xid + 12582912;                   // 12582912: y / o bf16
    // d_out (f32, 16384x768): xe (patch GEMM -> LN), then final output

    // ---- weight prep ----
    convert_bf16_kernel<<<(589824 + 255) / 256, 256, 0, stream>>>(patch_w, wPatch, 589824);
    transpose_to_bf16_kernel<<<(1769472 + 255) / 256, 256, 0, stream>>>(qkv_w, wQkvT, D, TD);
    transpose_to_bf16_kernel<<<(589824 + 255) / 256, 256, 0, stream>>>(proj_w, wProjT, D, D);
    transpose_to_bf16_kernel<<<(2359296 + 255) / 256, 256, 0, stream>>>(ff1_w, wFf1T, D, F);
    transpose_to_bf16_kernel<<<(2359296 + 255) / 256, 256, 0, stream>>>(ff2_w, wFf2T, F, D);

    // ---- pipeline ----
    im2col_kernel<<<(MN * 768) / 256, 256, 0, stream>>>(input, bigBuf);

    // G1: xe = im2col @ patch_w^T + patch_b  -> d_out (f32)
    gemm128_kernel<<<(D / 128) * NY, 256, 0, stream>>>(bigBuf, wPatch, patch_b, nullptr,
                                                       out, nullptr, MN, D, 768, 768, 0, 0);
    // LN + PE -> xid (bf16 identity + GEMM input)
    ln_pe_kernel<<<MN, 256, 0, stream>>>(out, ln_g, ln_b, xid);

    // FF#1: h = gelu(xid @ ff1 + b1) -> bigBuf (bf16, 100.7 MB)
    gemm128_kernel<<<(F / 128) * NY, 256, 0, stream>>>(xid, wFf1T, ff1_b, nullptr,
                                                       nullptr, bigBuf, MN, F, 768, 768, 1, 0);
    // y = h @ ff2 + b2 -> t0 (bf16)
    gemm128_kernel<<<(D / 128) * NY, 256, 0, stream>>>(bigBuf, wFf2T, ff2_b, nullptr,
                                                       nullptr, t0, MN, D, F, F, 0, 0);
    // qkv = y @ qkv_w + qkv_b -> bigBuf (bf16, 75.5 MB; h dead)
    gemm128_kernel<<<(TD / 128) * NY, 256, 0, stream>>>(t0, wQkvT, qkv_b, nullptr,
                                                        nullptr, bigBuf, MN, TD, 768, 768, 0, 0);
    // attention -> o (bf16) into t0
    attn_kernel<<<16 * 16 * 12, 256, 0, stream>>>(bigBuf, t0);

    // x2 = o @ proj + proj_b + identity(xid) -> xid (bf16; in-place per-element safe)
    gemm128_kernel<<<(D / 128) * NY, 256, 0, stream>>>(t0, wProjT, proj_b, xid,
                                                       nullptr, xid, MN, D, 768, 768, 0, 0);

    // FF#2: h2 = gelu(x2 @ ff1 + b1) -> bigBuf (qkv dead)
    gemm128_kernel<<<(F / 128) * NY, 256, 0, stream>>>(xid, wFf1T, ff1_b, nullptr,
                                                       nullptr, bigBuf, MN, F, 768, 768, 1, 0);
    // out = h2 @ ff2 + b2 + x2(bf16 resid)  (f32, final)
    gemm128_kernel<<<(D / 128) * NY, 256, 0, stream>>>(bigBuf, wFf2T, ff2_b, xid,
                                                       out, nullptr, MN, D, F, F, 0, 0);
}